// Round 20
// baseline (60822.137 us; speedup 1.0000x reference)
//
#include <hip/hip_runtime.h>
#include <cstdint>

#pragma clang fp contract(off)

typedef unsigned char u8;

// Round-11 faithful-f32 baseline, ONE knob: all 1x1-conv/fc channel sums use
// BLAS-style kc=256 blocking — sequential within each 256-chunk, chunk sums
// accumulated sequentially (C += block), emulating the Eigen/oneDNN GEMM
// realization that produced the stored reference output.

__device__ __forceinline__ void lif_step(float& mem, float& spk, float v) {
    float m1 = __fmul_rn(mem, 0.25f);            // exact (pow2)
    float m2 = __fmul_rn(m1, (1.0f - spk));      // exact (x0 or x1)
    mem = __fadd_rn(m2, v);                      // one rounding
    spk = (mem > 0.5f) ? 1.0f : 0.0f;
}

// kc=256-blocked sparse weight sum: seq within chunk, chunks seq-combined.
__device__ __forceinline__ float sum_kc256(const u8* Sg, const float* Wo, int C) {
    float acc = 0.0f;
    for (int c0 = 0; c0 < C; c0 += 256) {
        float part = 0.0f;
        for (int c = c0; c < c0 + 256; ++c)
            if (Sg[(size_t)c * 576]) part = __fadd_rn(part, Wo[c]);
        acc = __fadd_rn(acc, part);
    }
    return acc;
}

// ---- LIF over T=4 from f32 source (+ optional pos broadcast) -> u8 ----
__global__ __launch_bounds__(256) void lif_f(const float* __restrict__ src,
                                             const float* __restrict__ pos,
                                             u8* __restrict__ dst,
                                             size_t plane, size_t cn) {
    size_t i = (size_t)blockIdx.x * 256 + threadIdx.x;
    if (i >= plane) return;
    float p = pos ? pos[i % cn] : 0.0f;
    float mem = 0.0f, spk = 0.0f;
#pragma unroll
    for (int t = 0; t < 4; ++t) {
        float v = src[(size_t)t * plane + i];
        if (pos) v = __fadd_rn(v, p);
        lif_step(mem, spk, v);
        dst[(size_t)t * plane + i] = (u8)spk;
    }
}

// ---- fused 1x1-conv + (acc[+c])*s+b + LIF: u8 -> u8 ----
__global__ __launch_bounds__(256) void pwlif(
    const float* __restrict__ W, const u8* __restrict__ S,
    const float* __restrict__ sc, const float* __restrict__ bi,
    const float* __restrict__ cb, u8* __restrict__ dst, int O, int C) {
    size_t i = (size_t)blockIdx.x * 256 + threadIdx.x;
    size_t total = (size_t)8 * O * 576;
    if (i >= total) return;
    int n = (int)(i % 576);
    int o = (int)((i / 576) % O);
    int b = (int)(i / ((size_t)O * 576));
    const float* Wo = W + (size_t)o * C;
    float s_ = sc[o], b_ = bi[o];
    float mem = 0.0f, spk = 0.0f;
#pragma unroll
    for (int t = 0; t < 4; ++t) {
        const u8* Sg = S + ((size_t)(t * 8 + b) * C) * 576 + n;
        float acc = sum_kc256(Sg, Wo, C);
        if (cb) acc = __fadd_rn(acc, cb[o]);
        float v = __fadd_rn(__fmul_rn(acc, s_), b_);
        lif_step(mem, spk, v);
        dst[((size_t)(t * 8 + b) * O + o) * 576 + n] = (u8)spk;
    }
}

// ---- fused depthwise 3x3 (cross-correlation, SAME, zero-pad) + BN + LIF ----
__global__ __launch_bounds__(256) void dwlif(
    const u8* __restrict__ in, const float* __restrict__ w9,
    const float* __restrict__ sc, const float* __restrict__ bi,
    u8* __restrict__ dst, int Ch) {
    size_t i = (size_t)blockIdx.x * 256 + threadIdx.x;
    size_t total = (size_t)8 * Ch * 576;
    if (i >= total) return;
    int n = (int)(i % 576);
    int c = (int)((i / 576) % Ch);
    int b = (int)(i / ((size_t)Ch * 576));
    int h = n / 24, w = n % 24;
    const float* wc = w9 + (size_t)c * 9;
    float s_ = sc[c], b_ = bi[c];
    float mem = 0.0f, spk = 0.0f;
#pragma unroll
    for (int t = 0; t < 4; ++t) {
        const u8* base = in + ((size_t)(t * 8 + b) * Ch + c) * 576;
        float acc = 0.0f;
#pragma unroll
        for (int ii = 0; ii < 3; ++ii) {
            int hh = h + ii - 1;
            if (hh < 0 || hh >= 24) continue;
#pragma unroll
            for (int jj = 0; jj < 3; ++jj) {
                int ww = w + jj - 1;
                if (ww < 0 || ww >= 24) continue;
                if (base[hh * 24 + ww]) acc = __fadd_rn(acc, wc[ii * 3 + jj]);
            }
        }
        float v = __fadd_rn(__fmul_rn(acc, s_), b_);
        lif_step(mem, spk, v);
        dst[((size_t)(t * 8 + b) * Ch + c) * 576 + n] = (u8)spk;
    }
}

// ---- pw + BN + residual(f32) -> f32 ----
__global__ __launch_bounds__(256) void pw_res(
    const float* __restrict__ W, const u8* __restrict__ S,
    const float* __restrict__ sc, const float* __restrict__ bi,
    const float* __restrict__ res, float* __restrict__ out, int O, int C) {
    size_t i = (size_t)blockIdx.x * 256 + threadIdx.x;
    size_t total = (size_t)8 * O * 576;
    if (i >= total) return;
    int n = (int)(i % 576);
    int o = (int)((i / 576) % O);
    int b = (int)(i / ((size_t)O * 576));
    const float* Wo = W + (size_t)o * C;
    float s_ = sc[o], b_ = bi[o];
#pragma unroll
    for (int t = 0; t < 4; ++t) {
        const u8* Sg = S + ((size_t)(t * 8 + b) * C) * 576 + n;
        float acc = sum_kc256(Sg, Wo, C);
        float v = __fadd_rn(__fmul_rn(acc, s_), b_);
        size_t idx = ((size_t)(t * 8 + b) * O + o) * 576 + n;
        out[idx] = __fadd_rn(res[idx], v);
    }
}

// ---- kv: integer dot of binary spikes (exact, order-free) ----
__global__ __launch_bounds__(256) void kvk(const u8* __restrict__ K,
                                           const u8* __restrict__ V,
                                           float* __restrict__ KV) {
    size_t i = (size_t)blockIdx.x * 256 + threadIdx.x;
    size_t total = (size_t)32 * 8 * 64 * 256;
    if (i >= total) return;
    int e = (int)(i % 256);
    int d = (int)((i / 256) % 64);
    int h = (int)((i / (256 * 64)) % 8);
    int g = (int)(i / (256 * 64 * 8));
    const u8* Kr = K + ((size_t)g * 512 + h * 64 + d) * 576;
    const u8* Vr = V + ((size_t)g * 2048 + h * 256 + e) * 576;
    int acc = 0;
    for (int n = 0; n < 576; ++n) acc += (int)(Kr[n] & Vr[n]);
    KV[i] = (float)acc;  // < 2^24: exact
}

// ---- o = 0.25 * q·kv (exact dyadic, order-free) + LIF -> u8 ----
__global__ __launch_bounds__(256) void olif(const u8* __restrict__ Q,
                                            const float* __restrict__ KV,
                                            u8* __restrict__ dst) {
    size_t i = (size_t)blockIdx.x * 256 + threadIdx.x;
    size_t total = (size_t)8 * 2048 * 576;
    if (i >= total) return;
    int n = (int)(i % 576);
    int ef = (int)((i / 576) % 2048);
    int b = (int)(i / ((size_t)2048 * 576));
    int h = ef >> 8, e = ef & 255;
    float mem = 0.0f, spk = 0.0f;
#pragma unroll
    for (int t = 0; t < 4; ++t) {
        int g = t * 8 + b;
        const u8* Qg = Q + ((size_t)g * 512 + h * 64) * 576 + n;
        const float* KVg = KV + ((size_t)g * 8 + h) * (64 * 256) + e;
        float acc = 0.0f;
        for (int d = 0; d < 64; ++d)
            if (Qg[(size_t)d * 576]) acc = __fadd_rn(acc, KVg[(size_t)d * 256]);
        float v = __fmul_rn(0.25f, acc);  // exact
        lif_step(mem, spk, v);
        dst[((size_t)g * 2048 + ef) * 576 + n] = (u8)spk;
    }
}

// ---- fc2: (acc+c)*s+b + residual -> f32 out ----
__global__ __launch_bounds__(256) void fc2_out(
    const float* __restrict__ W, const u8* __restrict__ S,
    const float* __restrict__ sc, const float* __restrict__ bi,
    const float* __restrict__ cb, const float* __restrict__ X3,
    float* __restrict__ out, int O, int C) {
    size_t i = (size_t)blockIdx.x * 256 + threadIdx.x;
    size_t total = (size_t)8 * O * 576;
    if (i >= total) return;
    int n = (int)(i % 576);
    int o = (int)((i / 576) % O);
    int b = (int)(i / ((size_t)O * 576));
    const float* Wo = W + (size_t)o * C;
    float s_ = sc[o], b_ = bi[o], c_ = cb[o];
#pragma unroll
    for (int t = 0; t < 4; ++t) {
        const u8* Sg = S + ((size_t)(t * 8 + b) * C) * 576 + n;
        float acc = sum_kc256(Sg, Wo, C);
        acc = __fadd_rn(acc, c_);
        float v = __fadd_rn(__fmul_rn(acc, s_), b_);
        size_t idx = ((size_t)(t * 8 + b) * O + o) * 576 + n;
        out[idx] = __fadd_rn(X3[idx], v);
    }
}

// ---------------------------------------------------------------------------
extern "C" void kernel_launch(void* const* d_in, const int* in_sizes, int n_in,
                              void* d_out, int out_size, void* d_ws, size_t ws_size,
                              hipStream_t stream) {
    const float* x        = (const float*)d_in[0];
    const float* pw1_w    = (const float*)d_in[1];
    const float* pw1_s    = (const float*)d_in[2];
    const float* pw1_b    = (const float*)d_in[3];
    const float* dw_w     = (const float*)d_in[4];
    const float* dw_s     = (const float*)d_in[5];
    const float* dw_b     = (const float*)d_in[6];
    const float* pw2_w    = (const float*)d_in[7];
    const float* pw2_s    = (const float*)d_in[8];
    const float* pw2_b    = (const float*)d_in[9];
    const float* s_pos    = (const float*)d_in[10];
    const float* q_w      = (const float*)d_in[11];
    const float* q_s      = (const float*)d_in[12];
    const float* q_b      = (const float*)d_in[13];
    const float* k_w      = (const float*)d_in[14];
    const float* k_s      = (const float*)d_in[15];
    const float* k_b      = (const float*)d_in[16];
    const float* v_w      = (const float*)d_in[17];
    const float* v_s      = (const float*)d_in[18];
    const float* v_b      = (const float*)d_in[19];
    const float* proj_w   = (const float*)d_in[20];
    const float* proj_s   = (const float*)d_in[21];
    const float* proj_b   = (const float*)d_in[22];
    const float* fc1_w    = (const float*)d_in[23];
    const float* fc1_c    = (const float*)d_in[24];
    const float* fc1_s    = (const float*)d_in[25];
    const float* fc1_b    = (const float*)d_in[26];
    const float* fc2_w    = (const float*)d_in[27];
    const float* fc2_c    = (const float*)d_in[28];
    const float* fc2_s    = (const float*)d_in[29];
    const float* fc2_b    = (const float*)d_in[30];
    float* out = (float*)d_out;
    (void)ws_size; (void)n_in; (void)in_sizes; (void)out_size;

    const size_t MB = 1024 * 1024;
    char* Wp = (char*)d_ws;
    float* X2 = (float*)(Wp);              // [0,40MB)   x2 -> x3 (f32, S1)
    float* KV = (float*)(Wp + 40 * MB);    // [40,60MB)  32*8*64*256 f32
    u8* U1 = (u8*)(Wp + 60 * MB);          // [60,70MB)  S1B: spk0/a/m
    u8* U2 = (u8*)(Wp + 70 * MB);          // [70,90MB)  2S1B: y1 / {k,q}
    u8* U3 = (u8*)(Wp + 90 * MB);          // [90,110MB) 2S1B: y2
    u8* U4 = (u8*)(Wp + 110 * MB);         // [110,148MB)4S1B: v -> f1
    u8* U5 = (u8*)(Wp + 150 * MB);         // [150,188MB)4S1B: o_spk
    const size_t S1B = (size_t)4 * 8 * 512 * 576;  // 9,437,184

    const size_t planeC  = (size_t)8 * 512 * 576;
    const size_t plane2C = 2 * planeC;
    const size_t plane4C = 4 * planeC;
    auto nblk = [](size_t n) { return (unsigned)((n + 255) / 256); };

    // ---- SepConv ----
    lif_f<<<nblk(planeC), 256, 0, stream>>>(x, nullptr, U1, planeC, 1);
    pwlif<<<nblk(plane2C), 256, 0, stream>>>(pw1_w, U1, pw1_s, pw1_b, nullptr, U2, 1024, 512);
    dwlif<<<nblk(plane2C), 256, 0, stream>>>(U2, dw_w, dw_s, dw_b, U3, 1024);
    pw_res<<<nblk(planeC), 256, 0, stream>>>(pw2_w, U3, pw2_s, pw2_b, x, X2, 512, 1024);

    // ---- Attention (pos in LIF input only — baseline) ----
    lif_f<<<nblk(planeC), 256, 0, stream>>>(X2, s_pos, U1, planeC, (size_t)512 * 576);
    pwlif<<<nblk(planeC), 256, 0, stream>>>(k_w, U1, k_s, k_b, nullptr, U2, 512, 512);       // k
    pwlif<<<nblk(plane4C), 256, 0, stream>>>(v_w, U1, v_s, v_b, nullptr, U4, 2048, 512);     // v
    kvk<<<nblk((size_t)32 * 8 * 64 * 256), 256, 0, stream>>>(U2, U4, KV);
    pwlif<<<nblk(planeC), 256, 0, stream>>>(q_w, U1, q_s, q_b, nullptr, U2 + S1B, 512, 512); // q
    olif<<<nblk(plane4C), 256, 0, stream>>>(U2 + S1B, KV, U5);
    pw_res<<<nblk(planeC), 256, 0, stream>>>(proj_w, U5, proj_s, proj_b, X2, X2, 512, 2048); // x3

    // ---- MLP ----
    lif_f<<<nblk(planeC), 256, 0, stream>>>(X2, nullptr, U1, planeC, 1);
    pwlif<<<nblk(plane4C), 256, 0, stream>>>(fc1_w, U1, fc1_s, fc1_b, fc1_c, U4, 2048, 512);
    fc2_out<<<nblk(planeC), 256, 0, stream>>>(fc2_w, U4, fc2_s, fc2_b, fc2_c, X2, out, 512, 2048);
}

// Round 21
// 20334.123 us; speedup vs baseline: 2.9911x; 2.9911x over previous
//
#include <hip/hip_runtime.h>
#include <cstdint>

#pragma clang fp contract(off)

typedef unsigned char u8;

// PASSED baseline (r20): kc=256-blocked f32 sums. This round keeps the exact
// rounding sequence (seq within 256-chunk asc c, chunks seq, epilogue order,
// LIF chain) and restructures for speed:
//  - transposed spike layout [g][n][c] -> contiguous uchar16 loads
//  - 4 independent t-chains interleaved (ILP hides fadd latency)
//  - if(s)add -> fma(cvt_ubyte, w, p): bit-exact (products w*{0,1}; +0 exact)
//  - kv via bitpack+popcount, o-sum via fma (both exact integers, order-free)

__device__ __forceinline__ void lif_step(float& mem, float& spk, float v) {
    float m1 = __fmul_rn(mem, 0.25f);            // exact (pow2)
    float m2 = __fmul_rn(m1, (1.0f - spk));      // exact (x0 or x1)
    mem = __fadd_rn(m2, v);                      // one rounding
    spk = (mem > 0.5f) ? 1.0f : 0.0f;
}

__device__ __forceinline__ float ubf(uint32_t x, int j) {
    return (float)((x >> (j * 8)) & 0xffu);      // v_cvt_f32_ubyteN
}

// ---- LIF over T=4 from f32 source (+ optional pos broadcast) -> u8 ----
__global__ __launch_bounds__(256) void lif_f(const float* __restrict__ src,
                                             const float* __restrict__ pos,
                                             u8* __restrict__ dst,
                                             size_t plane, size_t cn) {
    size_t i = (size_t)blockIdx.x * 256 + threadIdx.x;
    if (i >= plane) return;
    float p = pos ? pos[i % cn] : 0.0f;
    float mem = 0.0f, spk = 0.0f;
#pragma unroll
    for (int t = 0; t < 4; ++t) {
        float v = src[(size_t)t * plane + i];
        if (pos) v = __fadd_rn(v, p);
        lif_step(mem, spk, v);
        dst[(size_t)t * plane + i] = (u8)spk;
    }
}

// ---- u8 transpose [g][R][576] -> [g][576][R], 32x32 LDS tiles ----
__global__ __launch_bounds__(256) void transp(const u8* __restrict__ in,
                                              u8* __restrict__ out, int R) {
    __shared__ u8 tile[32][33];
    int g = blockIdx.z;
    int r0 = blockIdx.y * 32;
    int n0 = blockIdx.x * 32;
    int tx = threadIdx.x & 31, ty = threadIdx.x >> 5;  // ty 0..7
    const u8* ip = in + ((size_t)g * R + r0) * 576 + n0;
#pragma unroll
    for (int k = 0; k < 4; ++k) {
        int r = ty + k * 8;
        tile[r][tx] = ip[(size_t)r * 576 + tx];
    }
    __syncthreads();
    u8* op = out + ((size_t)g * 576 + n0) * R + r0;
#pragma unroll
    for (int k = 0; k < 4; ++k) {
        int r = ty + k * 8;
        op[(size_t)r * R + tx] = tile[tx][r];
    }
}

// ---- transposed-input 1x1-conv + (acc[+cb])*s+b + LIF -> u8 std ----
// Bit-exact replica of r20 sum_kc256 + epilogue + lif_step.
__global__ __launch_bounds__(256) void pwlifT(
    const float* __restrict__ W, const u8* __restrict__ ST,
    const float* __restrict__ sc, const float* __restrict__ bi,
    const float* __restrict__ cb, u8* __restrict__ dst, int O, int C) {
    int lane = threadIdx.x & 63;
    int n = blockIdx.x * 64 + lane;
    int o = blockIdx.y * 4 + (threadIdx.x >> 6);
    int b = blockIdx.z;
    const float* Wo = W + (size_t)o * C;
    const u8* bt0 = ST + ((size_t)(0 * 8 + b) * 576 + n) * C;
    const u8* bt1 = ST + ((size_t)(1 * 8 + b) * 576 + n) * C;
    const u8* bt2 = ST + ((size_t)(2 * 8 + b) * 576 + n) * C;
    const u8* bt3 = ST + ((size_t)(3 * 8 + b) * 576 + n) * C;
    float a0 = 0.f, a1 = 0.f, a2 = 0.f, a3 = 0.f;
    for (int c0 = 0; c0 < C; c0 += 256) {
        float p0 = 0.f, p1 = 0.f, p2 = 0.f, p3 = 0.f;
#pragma unroll 4
        for (int cq = 0; cq < 256; cq += 16) {
            uint4 q0 = *(const uint4*)(bt0 + c0 + cq);
            uint4 q1 = *(const uint4*)(bt1 + c0 + cq);
            uint4 q2 = *(const uint4*)(bt2 + c0 + cq);
            uint4 q3 = *(const uint4*)(bt3 + c0 + cq);
            const float* wp = Wo + c0 + cq;
#pragma unroll
            for (int d = 0; d < 4; ++d) {
                uint32_t u0 = (&q0.x)[d], u1 = (&q1.x)[d];
                uint32_t u2 = (&q2.x)[d], u3 = (&q3.x)[d];
#pragma unroll
                for (int j = 0; j < 4; ++j) {
                    float w = wp[d * 4 + j];
                    p0 = __fmaf_rn(ubf(u0, j), w, p0);
                    p1 = __fmaf_rn(ubf(u1, j), w, p1);
                    p2 = __fmaf_rn(ubf(u2, j), w, p2);
                    p3 = __fmaf_rn(ubf(u3, j), w, p3);
                }
            }
        }
        a0 = __fadd_rn(a0, p0); a1 = __fadd_rn(a1, p1);
        a2 = __fadd_rn(a2, p2); a3 = __fadd_rn(a3, p3);
    }
    float s_ = sc[o], b_ = bi[o];
    float accs[4] = {a0, a1, a2, a3};
    float mem = 0.f, spk = 0.f;
    size_t planeO = (size_t)8 * O * 576;
#pragma unroll
    for (int t = 0; t < 4; ++t) {
        float acc = accs[t];
        if (cb) acc = __fadd_rn(acc, cb[o]);
        float v = __fadd_rn(__fmul_rn(acc, s_), b_);
        lif_step(mem, spk, v);
        dst[(size_t)t * planeO + ((size_t)b * O + o) * 576 + n] = (u8)spk;
    }
}

// ---- transposed-input 1x1-conv + (acc[+cb])*s+b + residual -> f32 std ----
__global__ __launch_bounds__(256) void pw_resT(
    const float* __restrict__ W, const u8* __restrict__ ST,
    const float* __restrict__ sc, const float* __restrict__ bi,
    const float* __restrict__ cb, const float* __restrict__ res,
    float* __restrict__ out, int O, int C) {
    int lane = threadIdx.x & 63;
    int n = blockIdx.x * 64 + lane;
    int o = blockIdx.y * 4 + (threadIdx.x >> 6);
    int b = blockIdx.z;
    const float* Wo = W + (size_t)o * C;
    const u8* bt0 = ST + ((size_t)(0 * 8 + b) * 576 + n) * C;
    const u8* bt1 = ST + ((size_t)(1 * 8 + b) * 576 + n) * C;
    const u8* bt2 = ST + ((size_t)(2 * 8 + b) * 576 + n) * C;
    const u8* bt3 = ST + ((size_t)(3 * 8 + b) * 576 + n) * C;
    float a0 = 0.f, a1 = 0.f, a2 = 0.f, a3 = 0.f;
    for (int c0 = 0; c0 < C; c0 += 256) {
        float p0 = 0.f, p1 = 0.f, p2 = 0.f, p3 = 0.f;
#pragma unroll 4
        for (int cq = 0; cq < 256; cq += 16) {
            uint4 q0 = *(const uint4*)(bt0 + c0 + cq);
            uint4 q1 = *(const uint4*)(bt1 + c0 + cq);
            uint4 q2 = *(const uint4*)(bt2 + c0 + cq);
            uint4 q3 = *(const uint4*)(bt3 + c0 + cq);
            const float* wp = Wo + c0 + cq;
#pragma unroll
            for (int d = 0; d < 4; ++d) {
                uint32_t u0 = (&q0.x)[d], u1 = (&q1.x)[d];
                uint32_t u2 = (&q2.x)[d], u3 = (&q3.x)[d];
#pragma unroll
                for (int j = 0; j < 4; ++j) {
                    float w = wp[d * 4 + j];
                    p0 = __fmaf_rn(ubf(u0, j), w, p0);
                    p1 = __fmaf_rn(ubf(u1, j), w, p1);
                    p2 = __fmaf_rn(ubf(u2, j), w, p2);
                    p3 = __fmaf_rn(ubf(u3, j), w, p3);
                }
            }
        }
        a0 = __fadd_rn(a0, p0); a1 = __fadd_rn(a1, p1);
        a2 = __fadd_rn(a2, p2); a3 = __fadd_rn(a3, p3);
    }
    float s_ = sc[o], b_ = bi[o];
    float accs[4] = {a0, a1, a2, a3};
    size_t planeO = (size_t)8 * O * 576;
#pragma unroll
    for (int t = 0; t < 4; ++t) {
        float acc = accs[t];
        if (cb) acc = __fadd_rn(acc, cb[o]);
        float v = __fadd_rn(__fmul_rn(acc, s_), b_);
        size_t idx = (size_t)t * planeO + ((size_t)b * O + o) * 576 + n;
        out[idx] = __fadd_rn(res[idx], v);
    }
}

// ---- fused depthwise 3x3 (cross-correlation, SAME, zero-pad) + BN + LIF ----
__global__ __launch_bounds__(256) void dwlif(
    const u8* __restrict__ in, const float* __restrict__ w9,
    const float* __restrict__ sc, const float* __restrict__ bi,
    u8* __restrict__ dst, int Ch) {
    size_t i = (size_t)blockIdx.x * 256 + threadIdx.x;
    size_t total = (size_t)8 * Ch * 576;
    if (i >= total) return;
    int n = (int)(i % 576);
    int c = (int)((i / 576) % Ch);
    int b = (int)(i / ((size_t)Ch * 576));
    int h = n / 24, w = n % 24;
    const float* wc = w9 + (size_t)c * 9;
    float s_ = sc[c], b_ = bi[c];
    float mem = 0.0f, spk = 0.0f;
#pragma unroll
    for (int t = 0; t < 4; ++t) {
        const u8* base = in + ((size_t)(t * 8 + b) * Ch + c) * 576;
        float acc = 0.0f;
#pragma unroll
        for (int ii = 0; ii < 3; ++ii) {
            int hh = h + ii - 1;
            if (hh < 0 || hh >= 24) continue;
#pragma unroll
            for (int jj = 0; jj < 3; ++jj) {
                int ww = w + jj - 1;
                if (ww < 0 || ww >= 24) continue;
                if (base[hh * 24 + ww]) acc = __fadd_rn(acc, wc[ii * 3 + jj]);
            }
        }
        float v = __fadd_rn(__fmul_rn(acc, s_), b_);
        lif_step(mem, spk, v);
        dst[((size_t)(t * 8 + b) * Ch + c) * 576 + n] = (u8)spk;
    }
}

// ---- bitpack spikes along n: [rows][576] u8 -> [rows][18] u32 ----
__global__ __launch_bounds__(256) void bitpack(const u8* __restrict__ in,
                                               uint32_t* __restrict__ out,
                                               size_t nwords) {
    size_t i = (size_t)blockIdx.x * 256 + threadIdx.x;
    if (i >= nwords) return;
    size_t r = i / 18; int w = (int)(i % 18);
    const u8* p = in + r * 576 + (size_t)w * 32;
    uint32_t m = 0;
#pragma unroll
    for (int j = 0; j < 32; ++j) m |= (p[j] ? 1u : 0u) << j;
    out[i] = m;
}

// ---- kv via AND+popcount (exact integer, order-free) ----
__global__ __launch_bounds__(256) void kvk_bit(const uint32_t* __restrict__ KP,
                                               const uint32_t* __restrict__ VP,
                                               float* __restrict__ KV) {
    int e = threadIdx.x;       // 0..255
    int h = blockIdx.x;        // 0..7
    int g = blockIdx.y;        // 0..31
    uint32_t v[18];
    const uint32_t* vp = VP + ((size_t)g * 2048 + h * 256 + e) * 18;
#pragma unroll
    for (int w = 0; w < 18; ++w) v[w] = vp[w];
    __shared__ uint32_t ks[64][18];
    const uint32_t* kp = KP + ((size_t)g * 512 + h * 64) * 18;
    for (int idx = threadIdx.x; idx < 64 * 18; idx += 256)
        ks[idx / 18][idx % 18] = kp[idx];
    __syncthreads();
    float* kvo = KV + ((size_t)(g * 8 + h)) * (64 * 256);
    for (int d = 0; d < 64; ++d) {
        int s = 0;
#pragma unroll
        for (int w = 0; w < 18; ++w) s += __popc(ks[d][w] & v[w]);
        kvo[d * 256 + e] = (float)s;  // exact int
    }
}

// ---- o = 0.25 * q.kv (exact ints) + LIF -> u8 std; q transposed ----
__global__ __launch_bounds__(64) void olifT(const u8* __restrict__ QT,
                                            const float* __restrict__ KV,
                                            u8* __restrict__ dst) {
    int n = blockIdx.x * 64 + threadIdx.x;
    int ef = blockIdx.y;
    int b = blockIdx.z;
    int h = ef >> 8, e = ef & 255;
    float mem = 0.f, spk = 0.f;
#pragma unroll
    for (int t = 0; t < 4; ++t) {
        int g = t * 8 + b;
        const u8* q = QT + ((size_t)g * 576 + n) * 512 + h * 64;
        const float* kvg = KV + ((size_t)(g * 8 + h)) * (64 * 256) + e;
        float acc = 0.f;
#pragma unroll
        for (int dq = 0; dq < 64; dq += 16) {
            uint4 qw = *(const uint4*)(q + dq);
#pragma unroll
            for (int d = 0; d < 4; ++d) {
                uint32_t u = (&qw.x)[d];
#pragma unroll
                for (int j = 0; j < 4; ++j)
                    acc = __fmaf_rn(ubf(u, j), kvg[(size_t)(dq + d * 4 + j) * 256], acc);
            }
        }
        float v = __fmul_rn(0.25f, acc);  // exact
        lif_step(mem, spk, v);
        dst[((size_t)g * 2048 + ef) * 576 + n] = (u8)spk;
    }
}

// ---------------------------------------------------------------------------
extern "C" void kernel_launch(void* const* d_in, const int* in_sizes, int n_in,
                              void* d_out, int out_size, void* d_ws, size_t ws_size,
                              hipStream_t stream) {
    const float* x        = (const float*)d_in[0];
    const float* pw1_w    = (const float*)d_in[1];
    const float* pw1_s    = (const float*)d_in[2];
    const float* pw1_b    = (const float*)d_in[3];
    const float* dw_w     = (const float*)d_in[4];
    const float* dw_s     = (const float*)d_in[5];
    const float* dw_b     = (const float*)d_in[6];
    const float* pw2_w    = (const float*)d_in[7];
    const float* pw2_s    = (const float*)d_in[8];
    const float* pw2_b    = (const float*)d_in[9];
    const float* s_pos    = (const float*)d_in[10];
    const float* q_w      = (const float*)d_in[11];
    const float* q_s      = (const float*)d_in[12];
    const float* q_b      = (const float*)d_in[13];
    const float* k_w      = (const float*)d_in[14];
    const float* k_s      = (const float*)d_in[15];
    const float* k_b      = (const float*)d_in[16];
    const float* v_w      = (const float*)d_in[17];
    const float* v_s      = (const float*)d_in[18];
    const float* v_b      = (const float*)d_in[19];
    const float* proj_w   = (const float*)d_in[20];
    const float* proj_s   = (const float*)d_in[21];
    const float* proj_b   = (const float*)d_in[22];
    const float* fc1_w    = (const float*)d_in[23];
    const float* fc1_c    = (const float*)d_in[24];
    const float* fc1_s    = (const float*)d_in[25];
    const float* fc1_b    = (const float*)d_in[26];
    const float* fc2_w    = (const float*)d_in[27];
    const float* fc2_c    = (const float*)d_in[28];
    const float* fc2_s    = (const float*)d_in[29];
    const float* fc2_b    = (const float*)d_in[30];
    float* out = (float*)d_out;
    (void)ws_size; (void)n_in; (void)in_sizes; (void)out_size;

    const size_t MB = 1024 * 1024;
    char* Wp = (char*)d_ws;
    float*    X2  = (float*)(Wp);             // [0,40MB)    x2 -> x3 f32
    float*    KV  = (float*)(Wp + 40 * MB);   // [40,60MB)
    u8*       A   = (u8*)(Wp + 60 * MB);      // [60,70MB)   S1B std
    u8*       AT  = (u8*)(Wp + 70 * MB);      // [70,80MB)   S1B transposed
    u8*       B   = (u8*)(Wp + 80 * MB);      // [80,100MB)  2S1B std (y1)
    u8*       BT  = (u8*)(Wp + 100 * MB);     // [100,120MB) 2S1B T (y2_T)
    u8*       C4  = (u8*)(Wp + 120 * MB);     // [120,158MB) 4S1B std
    u8*       C4T = (u8*)(Wp + 158 * MB);     // [158,196MB) 4S1B T
    uint32_t* KP  = (uint32_t*)(Wp + 196 * MB);  // 1.2MB
    uint32_t* VP  = (uint32_t*)(Wp + 198 * MB);  // 4.8MB -> ends 203MB

    const size_t planeC = (size_t)8 * 512 * 576;
    auto nblk = [](size_t n) { return (unsigned)((n + 255) / 256); };

    // ---- SepConv ----
    lif_f<<<nblk(planeC), 256, 0, stream>>>(x, nullptr, A, planeC, 1);
    transp<<<dim3(18, 16, 32), 256, 0, stream>>>(A, AT, 512);
    pwlifT<<<dim3(9, 256, 8), 256, 0, stream>>>(pw1_w, AT, pw1_s, pw1_b, nullptr, B, 1024, 512);
    dwlif<<<nblk((size_t)8 * 1024 * 576), 256, 0, stream>>>(B, dw_w, dw_s, dw_b, C4, 1024);
    transp<<<dim3(18, 32, 32), 256, 0, stream>>>(C4, BT, 1024);
    pw_resT<<<dim3(9, 128, 8), 256, 0, stream>>>(pw2_w, BT, pw2_s, pw2_b, nullptr, x, X2, 512, 1024);

    // ---- Attention ----
    lif_f<<<nblk(planeC), 256, 0, stream>>>(X2, s_pos, A, planeC, (size_t)512 * 576);
    transp<<<dim3(18, 16, 32), 256, 0, stream>>>(A, AT, 512);
    pwlifT<<<dim3(9, 128, 8), 256, 0, stream>>>(k_w, AT, k_s, k_b, nullptr, A, 512, 512);
    bitpack<<<nblk((size_t)32 * 512 * 18), 256, 0, stream>>>(A, KP, (size_t)32 * 512 * 18);
    pwlifT<<<dim3(9, 512, 8), 256, 0, stream>>>(v_w, AT, v_s, v_b, nullptr, C4, 2048, 512);
    bitpack<<<nblk((size_t)32 * 2048 * 18), 256, 0, stream>>>(C4, VP, (size_t)32 * 2048 * 18);
    kvk_bit<<<dim3(8, 32), 256, 0, stream>>>(KP, VP, KV);
    pwlifT<<<dim3(9, 128, 8), 256, 0, stream>>>(q_w, AT, q_s, q_b, nullptr, A, 512, 512);
    transp<<<dim3(18, 16, 32), 256, 0, stream>>>(A, AT, 512);   // q_T (a_T dead)
    olifT<<<dim3(9, 2048, 8), 64, 0, stream>>>(AT, KV, C4);     // o_spk (v dead)
    transp<<<dim3(18, 64, 32), 256, 0, stream>>>(C4, C4T, 2048);
    pw_resT<<<dim3(9, 128, 8), 256, 0, stream>>>(proj_w, C4T, proj_s, proj_b, nullptr, X2, X2, 512, 2048);

    // ---- MLP ----
    lif_f<<<nblk(planeC), 256, 0, stream>>>(X2, nullptr, A, planeC, 1);
    transp<<<dim3(18, 16, 32), 256, 0, stream>>>(A, AT, 512);
    pwlifT<<<dim3(9, 512, 8), 256, 0, stream>>>(fc1_w, AT, fc1_s, fc1_b, fc1_c, C4, 2048, 512);
    transp<<<dim3(18, 64, 32), 256, 0, stream>>>(C4, C4T, 2048);
    pw_resT<<<dim3(9, 128, 8), 256, 0, stream>>>(fc2_w, C4T, fc2_s, fc2_b, fc2_c, X2, out, 512, 2048);
}

// Round 23
// 3398.016 us; speedup vs baseline: 17.8993x; 5.9841x over previous
//
#include <hip/hip_runtime.h>
#include <cstdint>

#pragma clang fp contract(off)

typedef unsigned char u8;

// r21 PASSED (20.3ms, absmax 0.125). This round: LDS-tiled GEMMs with o-reuse
// (r22 fixed: macro -> template). BIT-EXACT constraint: per (o,t,n) acc =
// seq-ascending-c fma within each 256-chunk; chunk sums folded sequentially;
// epilogue (cb,*s,+b) + LIF chain identical to r20.

__device__ __forceinline__ void lif_step(float& mem, float& spk, float v) {
    float m1 = __fmul_rn(mem, 0.25f);            // exact (pow2)
    float m2 = __fmul_rn(m1, (1.0f - spk));      // exact (x0 or x1)
    mem = __fadd_rn(m2, v);                      // one rounding
    spk = (mem > 0.5f) ? 1.0f : 0.0f;
}

__device__ __forceinline__ float ubf(uint32_t x, int j) {
    return (float)((x >> (j * 8)) & 0xffu);      // v_cvt_f32_ubyteN
}

// ---- LIF over T=4 from f32 source (+ optional pos broadcast) -> u8 ----
__global__ __launch_bounds__(256) void lif_f(const float* __restrict__ src,
                                             const float* __restrict__ pos,
                                             u8* __restrict__ dst,
                                             size_t plane, size_t cn) {
    size_t i = (size_t)blockIdx.x * 256 + threadIdx.x;
    if (i >= plane) return;
    float p = pos ? pos[i % cn] : 0.0f;
    float mem = 0.0f, spk = 0.0f;
#pragma unroll
    for (int t = 0; t < 4; ++t) {
        float v = src[(size_t)t * plane + i];
        if (pos) v = __fadd_rn(v, p);
        lif_step(mem, spk, v);
        dst[(size_t)t * plane + i] = (u8)spk;
    }
}

// ---- u8 transpose [g][R][576] -> [g][576][R], 32x32 LDS tiles ----
__global__ __launch_bounds__(256) void transp(const u8* __restrict__ in,
                                              u8* __restrict__ out, int R) {
    __shared__ u8 tile[32][33];
    int g = blockIdx.z;
    int r0 = blockIdx.y * 32;
    int n0 = blockIdx.x * 32;
    int tx = threadIdx.x & 31, ty = threadIdx.x >> 5;  // ty 0..7
    const u8* ip = in + ((size_t)g * R + r0) * 576 + n0;
#pragma unroll
    for (int k = 0; k < 4; ++k) {
        int r = ty + k * 8;
        tile[r][tx] = ip[(size_t)r * 576 + tx];
    }
    __syncthreads();
    u8* op = out + ((size_t)g * 576 + n0) * R + r0;
#pragma unroll
    for (int k = 0; k < 4; ++k) {
        int r = ty + k * 8;
        op[(size_t)r * R + tx] = tile[tx][r];
    }
}

// ===========================================================================
// Tiled 1x1-conv: block = 64n x 32o, b fixed. LDS-staged 128-c slices.
// p[8][4] in-chunk accs (ascending c), a[8][4] folded at 256-c boundaries.
// DO_LIF=1: BN+LIF -> u8 dst.  DO_LIF=0: BN+residual -> f32 outp.
// ===========================================================================
template <int DO_LIF>
__global__ __launch_bounds__(256) void pw_tile(
    const float* __restrict__ W, const u8* __restrict__ ST,
    const float* __restrict__ sc, const float* __restrict__ bi,
    const float* __restrict__ cb, const float* __restrict__ res,
    u8* __restrict__ dst, float* __restrict__ outp, int O, int C) {
    __shared__ u8 spk[4][64][144];
    __shared__ float wt[32][132];
    int lane = threadIdx.x & 63;
    int wave = threadIdx.x >> 6;
    int n0 = blockIdx.x * 64;
    int o0 = blockIdx.y * 32;
    int b = blockIdx.z;
    int n = n0 + lane;
    int wo = wave * 8;
    float a[8][4] = {}, p[8][4] = {};
    for (int c0 = 0; c0 < C; c0 += 256) {
        for (int s = 0; s < 2; ++s) {
            int cs = c0 + s * 128;
            __syncthreads();
            {   // stage spikes: 256 rows (4t x 64n), 128B each
                int t = threadIdx.x >> 6, nl = threadIdx.x & 63;
                const uint4* g4 = (const uint4*)(ST +
                    ((size_t)(t * 8 + b) * 576 + n0 + nl) * C + cs);
                uint4* l4 = (uint4*)&spk[t][nl][0];
#pragma unroll
                for (int q = 0; q < 8; ++q) l4[q] = g4[q];
            }
            {   // stage weights: 32 rows x 128 f32
                int row = threadIdx.x >> 3, seg = (threadIdx.x & 7) * 16;
                const float4* gw = (const float4*)(W +
                    (size_t)(o0 + row) * C + cs + seg);
                float4* lw = (float4*)&wt[row][seg];
#pragma unroll
                for (int q = 0; q < 4; ++q) lw[q] = gw[q];
            }
            __syncthreads();
            for (int cq = 0; cq < 128; cq += 16) {
                uint4 s0 = *(const uint4*)&spk[0][lane][cq];
                uint4 s1 = *(const uint4*)&spk[1][lane][cq];
                uint4 s2 = *(const uint4*)&spk[2][lane][cq];
                uint4 s3 = *(const uint4*)&spk[3][lane][cq];
#pragma unroll
                for (int d = 0; d < 4; ++d) {
                    float4 wk[8];
#pragma unroll
                    for (int k = 0; k < 8; ++k)
                        wk[k] = *(const float4*)&wt[wo + k][cq + d * 4];
                    uint32_t u0 = (&s0.x)[d], u1 = (&s1.x)[d];
                    uint32_t u2 = (&s2.x)[d], u3 = (&s3.x)[d];
#pragma unroll
                    for (int j = 0; j < 4; ++j) {
                        float f0 = ubf(u0, j), f1 = ubf(u1, j);
                        float f2 = ubf(u2, j), f3 = ubf(u3, j);
#pragma unroll
                        for (int k = 0; k < 8; ++k) {
                            float w = (&wk[k].x)[j];
                            p[k][0] = __fmaf_rn(f0, w, p[k][0]);
                            p[k][1] = __fmaf_rn(f1, w, p[k][1]);
                            p[k][2] = __fmaf_rn(f2, w, p[k][2]);
                            p[k][3] = __fmaf_rn(f3, w, p[k][3]);
                        }
                    }
                }
            }
        }
#pragma unroll
        for (int k = 0; k < 8; ++k)
#pragma unroll
            for (int t = 0; t < 4; ++t) {
                a[k][t] = __fadd_rn(a[k][t], p[k][t]);
                p[k][t] = 0.0f;
            }
    }
    size_t planeO = (size_t)8 * O * 576;
#pragma unroll
    for (int k = 0; k < 8; ++k) {
        int o = o0 + wo + k;
        float s_ = sc[o], b_ = bi[o];
        if (DO_LIF) {
            float mem = 0.f, spkr = 0.f;
#pragma unroll
            for (int t = 0; t < 4; ++t) {
                float acc = a[k][t];
                if (cb) acc = __fadd_rn(acc, cb[o]);
                float v = __fadd_rn(__fmul_rn(acc, s_), b_);
                lif_step(mem, spkr, v);
                dst[(size_t)t * planeO + ((size_t)b * O + o) * 576 + n] = (u8)spkr;
            }
        } else {
#pragma unroll
            for (int t = 0; t < 4; ++t) {
                float acc = a[k][t];
                if (cb) acc = __fadd_rn(acc, cb[o]);
                float v = __fadd_rn(__fmul_rn(acc, s_), b_);
                size_t idx = (size_t)t * planeO + ((size_t)b * O + o) * 576 + n;
                outp[idx] = __fadd_rn(res[idx], v);
            }
        }
    }
}

// ---- fused depthwise 3x3 (cross-correlation, SAME, zero-pad) + BN + LIF ----
__global__ __launch_bounds__(256) void dwlif(
    const u8* __restrict__ in, const float* __restrict__ w9,
    const float* __restrict__ sc, const float* __restrict__ bi,
    u8* __restrict__ dst, int Ch) {
    size_t i = (size_t)blockIdx.x * 256 + threadIdx.x;
    size_t total = (size_t)8 * Ch * 576;
    if (i >= total) return;
    int n = (int)(i % 576);
    int c = (int)((i / 576) % Ch);
    int b = (int)(i / ((size_t)Ch * 576));
    int h = n / 24, w = n % 24;
    const float* wc = w9 + (size_t)c * 9;
    float s_ = sc[c], b_ = bi[c];
    float mem = 0.0f, spk = 0.0f;
#pragma unroll
    for (int t = 0; t < 4; ++t) {
        const u8* base = in + ((size_t)(t * 8 + b) * Ch + c) * 576;
        float acc = 0.0f;
#pragma unroll
        for (int ii = 0; ii < 3; ++ii) {
            int hh = h + ii - 1;
            if (hh < 0 || hh >= 24) continue;
#pragma unroll
            for (int jj = 0; jj < 3; ++jj) {
                int ww = w + jj - 1;
                if (ww < 0 || ww >= 24) continue;
                if (base[hh * 24 + ww]) acc = __fadd_rn(acc, wc[ii * 3 + jj]);
            }
        }
        float v = __fadd_rn(__fmul_rn(acc, s_), b_);
        lif_step(mem, spk, v);
        dst[((size_t)(t * 8 + b) * Ch + c) * 576 + n] = (u8)spk;
    }
}

// ---- bitpack spikes along n: [rows][576] u8 -> [rows][18] u32 ----
__global__ __launch_bounds__(256) void bitpack(const u8* __restrict__ in,
                                               uint32_t* __restrict__ out,
                                               size_t nwords) {
    size_t i = (size_t)blockIdx.x * 256 + threadIdx.x;
    if (i >= nwords) return;
    size_t r = i / 18; int w = (int)(i % 18);
    const u8* p = in + r * 576 + (size_t)w * 32;
    uint32_t m = 0;
#pragma unroll
    for (int j = 0; j < 32; ++j) m |= (p[j] ? 1u : 0u) << j;
    out[i] = m;
}

// ---- kv via AND+popcount (exact integer, order-free) ----
__global__ __launch_bounds__(256) void kvk_bit(const uint32_t* __restrict__ KP,
                                               const uint32_t* __restrict__ VP,
                                               float* __restrict__ KV) {
    int e = threadIdx.x;       // 0..255
    int h = blockIdx.x;        // 0..7
    int g = blockIdx.y;        // 0..31
    uint32_t v[18];
    const uint32_t* vp = VP + ((size_t)g * 2048 + h * 256 + e) * 18;
#pragma unroll
    for (int w = 0; w < 18; ++w) v[w] = vp[w];
    __shared__ uint32_t ks[64][18];
    const uint32_t* kp = KP + ((size_t)g * 512 + h * 64) * 18;
    for (int idx = threadIdx.x; idx < 64 * 18; idx += 256)
        ks[idx / 18][idx % 18] = kp[idx];
    __syncthreads();
    float* kvo = KV + ((size_t)(g * 8 + h)) * (64 * 256);
    for (int d = 0; d < 64; ++d) {
        int s = 0;
#pragma unroll
        for (int w = 0; w < 18; ++w) s += __popc(ks[d][w] & v[w]);
        kvo[d * 256 + e] = (float)s;  // exact int
    }
}

// ---- o = 0.25 * q.kv (exact ints) + LIF -> u8 std; q transposed ----
__global__ __launch_bounds__(64) void olifT(const u8* __restrict__ QT,
                                            const float* __restrict__ KV,
                                            u8* __restrict__ dst) {
    int n = blockIdx.x * 64 + threadIdx.x;
    int ef = blockIdx.y;
    int b = blockIdx.z;
    int h = ef >> 8, e = ef & 255;
    float mem = 0.f, spk = 0.f;
#pragma unroll
    for (int t = 0; t < 4; ++t) {
        int g = t * 8 + b;
        const u8* q = QT + ((size_t)g * 576 + n) * 512 + h * 64;
        const float* kvg = KV + ((size_t)(g * 8 + h)) * (64 * 256) + e;
        float acc = 0.f;
#pragma unroll
        for (int dq = 0; dq < 64; dq += 16) {
            uint4 qw = *(const uint4*)(q + dq);
#pragma unroll
            for (int d = 0; d < 4; ++d) {
                uint32_t u = (&qw.x)[d];
#pragma unroll
                for (int j = 0; j < 4; ++j)
                    acc = __fmaf_rn(ubf(u, j), kvg[(size_t)(dq + d * 4 + j) * 256], acc);
            }
        }
        float v = __fmul_rn(0.25f, acc);  // exact
        lif_step(mem, spk, v);
        dst[((size_t)g * 2048 + ef) * 576 + n] = (u8)spk;
    }
}

// ---------------------------------------------------------------------------
extern "C" void kernel_launch(void* const* d_in, const int* in_sizes, int n_in,
                              void* d_out, int out_size, void* d_ws, size_t ws_size,
                              hipStream_t stream) {
    const float* x        = (const float*)d_in[0];
    const float* pw1_w    = (const float*)d_in[1];
    const float* pw1_s    = (const float*)d_in[2];
    const float* pw1_b    = (const float*)d_in[3];
    const float* dw_w     = (const float*)d_in[4];
    const float* dw_s     = (const float*)d_in[5];
    const float* dw_b     = (const float*)d_in[6];
    const float* pw2_w    = (const float*)d_in[7];
    const float* pw2_s    = (const float*)d_in[8];
    const float* pw2_b    = (const float*)d_in[9];
    const float* s_pos    = (const float*)d_in[10];
    const float* q_w      = (const float*)d_in[11];
    const float* q_s      = (const float*)d_in[12];
    const float* q_b      = (const float*)d_in[13];
    const float* k_w      = (const float*)d_in[14];
    const float* k_s      = (const float*)d_in[15];
    const float* k_b      = (const float*)d_in[16];
    const float* v_w      = (const float*)d_in[17];
    const float* v_s      = (const float*)d_in[18];
    const float* v_b      = (const float*)d_in[19];
    const float* proj_w   = (const float*)d_in[20];
    const float* proj_s   = (const float*)d_in[21];
    const float* proj_b   = (const float*)d_in[22];
    const float* fc1_w    = (const float*)d_in[23];
    const float* fc1_c    = (const float*)d_in[24];
    const float* fc1_s    = (const float*)d_in[25];
    const float* fc1_b    = (const float*)d_in[26];
    const float* fc2_w    = (const float*)d_in[27];
    const float* fc2_c    = (const float*)d_in[28];
    const float* fc2_s    = (const float*)d_in[29];
    const float* fc2_b    = (const float*)d_in[30];
    float* out = (float*)d_out;
    (void)ws_size; (void)n_in; (void)in_sizes; (void)out_size;

    const size_t MB = 1024 * 1024;
    char* Wp = (char*)d_ws;
    float*    X2  = (float*)(Wp);             // [0,40MB)    x2 -> x3 f32
    float*    KV  = (float*)(Wp + 40 * MB);   // [40,60MB)
    u8*       A   = (u8*)(Wp + 60 * MB);      // [60,70MB)   S1B std
    u8*       AT  = (u8*)(Wp + 70 * MB);      // [70,80MB)   S1B transposed
    u8*       B   = (u8*)(Wp + 80 * MB);      // [80,100MB)  2S1B std (y1)
    u8*       BT  = (u8*)(Wp + 100 * MB);     // [100,120MB) 2S1B T (y2_T)
    u8*       C4  = (u8*)(Wp + 120 * MB);     // [120,158MB) 4S1B std
    u8*       C4T = (u8*)(Wp + 158 * MB);     // [158,196MB) 4S1B T
    uint32_t* KP  = (uint32_t*)(Wp + 196 * MB);  // 1.2MB
    uint32_t* VP  = (uint32_t*)(Wp + 198 * MB);  // 4.8MB -> ends 203MB

    const size_t planeC = (size_t)8 * 512 * 576;
    auto nblk = [](size_t n) { return (unsigned)((n + 255) / 256); };

    // ---- SepConv ----
    lif_f<<<nblk(planeC), 256, 0, stream>>>(x, nullptr, A, planeC, 1);
    transp<<<dim3(18, 16, 32), 256, 0, stream>>>(A, AT, 512);
    pw_tile<1><<<dim3(9, 32, 8), 256, 0, stream>>>(pw1_w, AT, pw1_s, pw1_b,
        nullptr, nullptr, B, nullptr, 1024, 512);
    dwlif<<<nblk((size_t)8 * 1024 * 576), 256, 0, stream>>>(B, dw_w, dw_s, dw_b, C4, 1024);
    transp<<<dim3(18, 32, 32), 256, 0, stream>>>(C4, BT, 1024);
    pw_tile<0><<<dim3(9, 16, 8), 256, 0, stream>>>(pw2_w, BT, pw2_s, pw2_b,
        nullptr, x, nullptr, X2, 512, 1024);

    // ---- Attention ----
    lif_f<<<nblk(planeC), 256, 0, stream>>>(X2, s_pos, A, planeC, (size_t)512 * 576);
    transp<<<dim3(18, 16, 32), 256, 0, stream>>>(A, AT, 512);
    pw_tile<1><<<dim3(9, 16, 8), 256, 0, stream>>>(k_w, AT, k_s, k_b,
        nullptr, nullptr, A, nullptr, 512, 512);
    bitpack<<<nblk((size_t)32 * 512 * 18), 256, 0, stream>>>(A, KP, (size_t)32 * 512 * 18);
    pw_tile<1><<<dim3(9, 64, 8), 256, 0, stream>>>(v_w, AT, v_s, v_b,
        nullptr, nullptr, C4, nullptr, 2048, 512);
    bitpack<<<nblk((size_t)32 * 2048 * 18), 256, 0, stream>>>(C4, VP, (size_t)32 * 2048 * 18);
    kvk_bit<<<dim3(8, 32), 256, 0, stream>>>(KP, VP, KV);
    pw_tile<1><<<dim3(9, 16, 8), 256, 0, stream>>>(q_w, AT, q_s, q_b,
        nullptr, nullptr, A, nullptr, 512, 512);
    transp<<<dim3(18, 16, 32), 256, 0, stream>>>(A, AT, 512);   // q_T (a_T dead)
    olifT<<<dim3(9, 2048, 8), 64, 0, stream>>>(AT, KV, C4);     // o_spk
    transp<<<dim3(18, 64, 32), 256, 0, stream>>>(C4, C4T, 2048);
    pw_tile<0><<<dim3(9, 16, 8), 256, 0, stream>>>(proj_w, C4T, proj_s, proj_b,
        nullptr, X2, nullptr, X2, 512, 2048);

    // ---- MLP ----
    lif_f<<<nblk(planeC), 256, 0, stream>>>(X2, nullptr, A, planeC, 1);
    transp<<<dim3(18, 16, 32), 256, 0, stream>>>(A, AT, 512);
    pw_tile<1><<<dim3(9, 64, 8), 256, 0, stream>>>(fc1_w, AT, fc1_s, fc1_b,
        fc1_c, nullptr, C4, nullptr, 2048, 512);
    transp<<<dim3(18, 64, 32), 256, 0, stream>>>(C4, C4T, 2048);
    pw_tile<0><<<dim3(9, 16, 8), 256, 0, stream>>>(fc2_w, C4T, fc2_s, fc2_b,
        fc2_c, X2, nullptr, out, 512, 2048);
}